// Round 3
// baseline (341.431 us; speedup 1.0000x reference)
//
#include <hip/hip_runtime.h>
#include <cstdint>
#include <cstddef>

#define HH 128
#define SLOPE 0.01f

typedef __attribute__((ext_vector_type(8))) __bf16 bf16x8;
typedef __attribute__((ext_vector_type(8))) unsigned short ushort8v;
typedef __attribute__((ext_vector_type(4))) float f32x4;

__device__ __forceinline__ float lrelu(float x) { return x >= 0.f ? x : SLOPE * x; }
__device__ __forceinline__ unsigned short f2b(float f) {
  union { float f; unsigned u; } v; v.f = f;
  unsigned r = v.u + 0x7fffu + ((v.u >> 16) & 1u);  // round-to-nearest-even
  return (unsigned short)(r >> 16);
}
__device__ __forceinline__ float b2f(unsigned short u) {
  union { unsigned u; float f; } v; v.u = ((unsigned)u) << 16; return v.f;
}

// LDS tile layout with XOR swizzle: element (r,k) of a [rows]x128 bf16 tile lives at
// lofs(r,k). 16B chunks (8 ushorts) stay contiguous; chunk index ^= (r&15).
__device__ __forceinline__ int lofs(int r, int k) {
  return (r << 7) + ((((k >> 3) ^ r) & 15) << 3) + (k & 7);
}

// Compiler fence + LDS drain within a wave (keeps capture-reads before overwrites).
#define WAVE_SYNC() asm volatile("s_waitcnt lgkmcnt(0)" ::: "memory")

// ---------------- CSR build ----------------

__global__ __launch_bounds__(256) void count_kernel(const int* __restrict__ dst,
                                                    int* __restrict__ cnt, int nE) {
  int e = blockIdx.x * 256 + threadIdx.x;
  if (e < nE) atomicAdd(&cnt[dst[e]], 1);
}

__global__ __launch_bounds__(1024) void scan1_kernel(int* __restrict__ cnt,
                                                     int* __restrict__ rowptr,
                                                     int* __restrict__ bsum,
                                                     float* __restrict__ dinv, int n) {
  __shared__ int wsum[16];
  const int tid = threadIdx.x;
  const int lane = tid & 63, wid = tid >> 6;
  int i = blockIdx.x * 1024 + tid;
  int v = (i < n) ? cnt[i] : 0;
  int x = v;
#pragma unroll
  for (int off = 1; off < 64; off <<= 1) {
    int y = __shfl_up(x, off, 64);
    if (lane >= off) x += y;
  }
  if (lane == 63) wsum[wid] = x;
  __syncthreads();
  if (tid == 0) {
    int s = 0;
#pragma unroll
    for (int w = 0; w < 16; ++w) { int t = wsum[w]; wsum[w] = s; s += t; }
    bsum[blockIdx.x] = s;
  }
  __syncthreads();
  if (i < n) {
    rowptr[i] = wsum[wid] + x - v;  // local exclusive
    dinv[i] = rsqrtf((float)v + 1.0f);
    cnt[i] = 0;
  }
}

__global__ __launch_bounds__(64) void scan2_kernel(int* __restrict__ bsum, int nb,
                                                   int* __restrict__ rowptr, int n, int E) {
  int lane = threadIdx.x;
  int v = (lane < nb) ? bsum[lane] : 0;
  int x = v;
#pragma unroll
  for (int off = 1; off < 64; off <<= 1) {
    int y = __shfl_up(x, off, 64);
    if (lane >= off) x += y;
  }
  if (lane < nb) bsum[lane] = x - v;  // exclusive
  if (lane == 0) rowptr[n] = E;
}

__global__ __launch_bounds__(1024) void scan3_kernel(int* __restrict__ rowptr,
                                                     const int* __restrict__ bsum, int n) {
  int i = blockIdx.x * 1024 + threadIdx.x;
  if (i < n) rowptr[i] += bsum[blockIdx.x];
}

// csr entry: .x = src node, .y = norm (float bits)
__global__ __launch_bounds__(256) void fill_kernel(const int* __restrict__ src,
                                                   const int* __restrict__ dst,
                                                   const int* __restrict__ rowptr,
                                                   int* __restrict__ cursor,
                                                   const float* __restrict__ dinv,
                                                   int2* __restrict__ csr, int nE) {
  int e = blockIdx.x * 256 + threadIdx.x;
  if (e >= nE) return;
  int d = dst[e], s = src[e];
  int pos = rowptr[d] + atomicAdd(&cursor[d], 1);
  int2 ent;
  ent.x = s;
  ent.y = __float_as_int(dinv[s] * dinv[d]);
  csr[pos] = ent;
}

// ---------------- weight pack: B-fragment order for mfma 16x16x32 ----------------
__global__ __launch_bounds__(256) void pack_kernel(const float* W0, const float* W1,
                                                   const float* W2, const float* W3,
                                                   const float* W4, const float* W5,
                                                   unsigned short* __restrict__ out) {
  const float* Ws[6] = {W0, W1, W2, W3, W4, W5};
  const float* W = Ws[blockIdx.y];
  int f = blockIdx.x * 256 + threadIdx.x;  // 0..16383
  int j = f & 7, L = (f >> 3) & 63, c = (f >> 9) & 7, t = f >> 12;
  int k = t * 32 + (L >> 4) * 8 + j;
  int n = c * 16 + (L & 15);
  out[(size_t)blockIdx.y * 16384 + f] = f2b(W[k * HH + n]);
}

// ---------------- shared device helpers ----------------

// 32-row (2 M-tile) MFMA stage; B-fragments come from LDS (block-shared weight
// copy, linear layout: fragment f at bytes [f*1024 + lane*16]). ds_read_b128 of
// contiguous 1KB per fragment = conflict-free, issued 8-deep per K-step.
__device__ __forceinline__ void mfma_w32_lds(const bf16x8 af[2][4],
                                             const unsigned short* __restrict__ Wl,
                                             int lane, f32x4 acc[2][8]) {
#pragma unroll
  for (int tt = 0; tt < 2; ++tt)
#pragma unroll
    for (int c = 0; c < 8; ++c) acc[tt][c] = (f32x4){0.f, 0.f, 0.f, 0.f};
#pragma unroll
  for (int t = 0; t < 4; ++t) {
    bf16x8 wf[8];
#pragma unroll
    for (int c = 0; c < 8; ++c) wf[c] = *(const bf16x8*)&Wl[(t * 8 + c) * 512 + lane * 8];
#pragma unroll
    for (int c = 0; c < 8; ++c)
#pragma unroll
      for (int tt = 0; tt < 2; ++tt)
        acc[tt][c] = __builtin_amdgcn_mfma_f32_16x16x32_bf16(af[tt][t], wf[c], acc[tt][c], 0, 0, 0);
  }
}

// A-fragments for both 16-row tiles from a 32-row swizzled LDS tile.
__device__ __forceinline__ void lds_afrags(const unsigned short* __restrict__ Tl,
                                           int m, int quad, bf16x8 af[2][4]) {
#pragma unroll
  for (int tt = 0; tt < 2; ++tt)
#pragma unroll
    for (int t = 0; t < 4; ++t)
      af[tt][t] = *(const bf16x8*)&Tl[lofs(tt * 16 + m, t * 32 + quad * 8)];
}

// ---------------- GEMM: A(fp32)[nrows,128] @ Wp -> bf16 out ----------------
// 8 waves/block, 32 rows/wave. Weights staged ONCE per block into LDS (32KB),
// then read as ds_read_b128 fragments — kills the per-wave global weight
// re-load that serialized r1/r2.

__global__ __launch_bounds__(512, 2) void gemm_conv(const float* __restrict__ A,
                                                    const unsigned short* __restrict__ Wp,
                                                    unsigned short* __restrict__ out, int nrows) {
  __shared__ __align__(16) unsigned short Wl[16384];
  const int tid = threadIdx.x;
  const int lane = tid & 63, wave = tid >> 6;
  const int row0 = blockIdx.x * 256 + wave * 32;
  const int m = lane & 15, quad = lane >> 4;

  // stage weights: each wave copies 4KB (4 chunks of 1KB)
  uint4 pw[4];
#pragma unroll
  for (int i = 0; i < 4; ++i) pw[i] = ((const uint4*)Wp)[(wave * 4 + i) * 64 + lane];
#pragma unroll
  for (int i = 0; i < 4; ++i) *(uint4*)&Wl[(wave * 4 + i) * 512 + lane * 8] = pw[i];

  // A fragments straight from global fp32, converted in-register
  bf16x8 af[2][4];
#pragma unroll
  for (int tt = 0; tt < 2; ++tt) {
    const int gr = row0 + tt * 16 + m;
    const bool rok = gr < nrows;
    const float* Arow = A + (size_t)gr * HH;
#pragma unroll
    for (int t = 0; t < 4; ++t) {
      const int k = t * 32 + quad * 8;
      float4 lo = make_float4(0.f, 0.f, 0.f, 0.f), hi = lo;
      if (rok) {
        lo = *(const float4*)(Arow + k);
        hi = *(const float4*)(Arow + k + 4);
      }
      union { ushort8v u; bf16x8 b; } cv;
      cv.u[0] = f2b(lo.x); cv.u[1] = f2b(lo.y); cv.u[2] = f2b(lo.z); cv.u[3] = f2b(lo.w);
      cv.u[4] = f2b(hi.x); cv.u[5] = f2b(hi.y); cv.u[6] = f2b(hi.z); cv.u[7] = f2b(hi.w);
      af[tt][t] = cv.b;
    }
  }

  __syncthreads();  // weights visible to all waves

  f32x4 acc[2][8];
  mfma_w32_lds(af, Wl, lane, acc);

#pragma unroll
  for (int tt = 0; tt < 2; ++tt)
#pragma unroll
    for (int c = 0; c < 8; ++c) {
      int col = c * 16 + m;
#pragma unroll
      for (int g = 0; g < 4; ++g) {
        int row = row0 + tt * 16 + quad * 4 + g;
        if (row < nrows) out[(size_t)row * HH + col] = f2b(acc[tt][c][g]);
      }
    }
}

// ---------------- agg: one wave per node ----------------
// out = leaky(sum norm*h[src] + self*dinv^2 + bias (+res fp32)); fp32 or bf16 out.

template <int RES, int OUTBF>
__global__ __launch_bounds__(256) void agg_kernel(const unsigned short* __restrict__ h,
                                                  const int* __restrict__ rowptr,
                                                  const int2* __restrict__ csr,
                                                  const float* __restrict__ dinv,
                                                  const float* __restrict__ bias,
                                                  const float* __restrict__ res,
                                                  void* __restrict__ outv, int n) {
  int node = blockIdx.x * 4 + (threadIdx.x >> 6);
  if (node >= n) return;
  int lane = threadIdx.x & 63;
  int c = lane << 1;
  int j = rowptr[node], end = rowptr[node + 1];
  float ax = 0.f, ay = 0.f;
  // 8-deep unroll: 8 outstanding gather loads per lane
  for (; j + 8 <= end; j += 8) {
    int2 e[8];
    ushort2 r[8];
#pragma unroll
    for (int q = 0; q < 8; ++q) e[q] = csr[j + q];
#pragma unroll
    for (int q = 0; q < 8; ++q) r[q] = *(const ushort2*)(h + (size_t)e[q].x * HH + c);
#pragma unroll
    for (int q = 0; q < 8; ++q) {
      float nv = __int_as_float(e[q].y);
      ax = fmaf(b2f(r[q].x), nv, ax); ay = fmaf(b2f(r[q].y), nv, ay);
    }
  }
  for (; j + 2 <= end; j += 2) {
    int2 e0 = csr[j], e1 = csr[j + 1];
    ushort2 r0 = *(const ushort2*)(h + (size_t)e0.x * HH + c);
    ushort2 r1 = *(const ushort2*)(h + (size_t)e1.x * HH + c);
    float n0 = __int_as_float(e0.y), n1 = __int_as_float(e1.y);
    ax = fmaf(b2f(r0.x), n0, ax); ay = fmaf(b2f(r0.y), n0, ay);
    ax = fmaf(b2f(r1.x), n1, ax); ay = fmaf(b2f(r1.y), n1, ay);
  }
  if (j < end) {
    int2 e0 = csr[j];
    float n0 = __int_as_float(e0.y);
    ushort2 r0 = *(const ushort2*)(h + (size_t)e0.x * HH + c);
    ax = fmaf(b2f(r0.x), n0, ax); ay = fmaf(b2f(r0.y), n0, ay);
  }
  float di = dinv[node], d2 = di * di;
  ushort2 hs = *(const ushort2*)(h + (size_t)node * HH + c);
  float2 b = *(const float2*)(bias + c);
  float ox = ax + b2f(hs.x) * d2 + b.x;
  float oy = ay + b2f(hs.y) * d2 + b.y;
  if (RES) {
    float2 r = *(const float2*)(res + (size_t)node * HH + c);
    ox += r.x; oy += r.y;
  }
  ox = lrelu(ox); oy = lrelu(oy);
  if (OUTBF) {
    ushort2 o; o.x = f2b(ox); o.y = f2b(oy);
    *(ushort2*)((unsigned short*)outv + (size_t)node * HH + c) = o;
  } else {
    *(float2*)((float*)outv + (size_t)node * HH + c) = make_float2(ox, oy);
  }
}

// ---------------- fusedMLP: 4-GEMM chain, 8 waves/block, LDS-shared weights ----
// Weights ping-pong through 2x32KB LDS buffers; W3/W4 prefetched to regs during
// stage 1/2 and ds_written right after the barrier frees the buffer. Each wave
// owns ONE 8KB tile buffer T: the f2 residual is captured into registers before
// stage 1's output overwrites T. gen is preloaded packed bf16 (r2 numerics).
// stage 1:  m  = leaky(f2@Wm1+bm1)                        -> T
// stage 2:  h3 = leaky(m@Wm2+bm2 + f2res); p=0.5*(h3+gen) -> T
// stage 3:  q  = leaky(p@Wp1+bp1)                         -> T
// stage 4:  out= leaky(q@Wp2+bp2)                         -> fp32 global

__global__ __launch_bounds__(512, 2) void fusedMLP(const unsigned short* __restrict__ f2bf,
                                                   const unsigned short* __restrict__ Wm1p,
                                                   const unsigned short* __restrict__ Wm2p,
                                                   const unsigned short* __restrict__ Wp1p,
                                                   const unsigned short* __restrict__ Wp2p,
                                                   const float* __restrict__ bm1,
                                                   const float* __restrict__ bm2,
                                                   const float* __restrict__ bp1,
                                                   const float* __restrict__ bp2,
                                                   const float* __restrict__ gen,
                                                   float* __restrict__ out, int n) {
  __shared__ __align__(16) unsigned short Wl[2][16384];   // 2 x 32KB weight ping-pong
  __shared__ __align__(16) unsigned short Tl[8][32 * HH]; // 8 x 8KB wave-private tiles
  const int tid = threadIdx.x;
  const int lane = tid & 63, wave = tid >> 6;
  const int row0 = blockIdx.x * 256 + wave * 32;
  const int m = lane & 15, quad = lane >> 4;
  unsigned short* T = Tl[wave];

  // --- prologue: stage W1 -> Wl[0], W2 -> Wl[1] (each wave moves 2x4KB) ---
  {
    uint4 pw[8];
#pragma unroll
    for (int i = 0; i < 8; ++i) {
      const unsigned short* Ws = (i < 4) ? Wm1p : Wm2p;
      pw[i] = ((const uint4*)Ws)[(wave * 4 + (i & 3)) * 64 + lane];
    }
#pragma unroll
    for (int i = 0; i < 8; ++i)
      *(uint4*)&Wl[i >> 2][(wave * 4 + (i & 3)) * 512 + lane * 8] = pw[i];
  }

  // --- stage f2 tile into T (swizzled) ---
#pragma unroll
  for (int i = 0; i < 8; ++i) {
    int idx = i * 64 + lane;            // 16B-chunk id 0..511
    int r = idx >> 4, k = (idx & 15) << 3;
    int gr = row0 + r;
    ushort8v v = {0, 0, 0, 0, 0, 0, 0, 0};
    if (gr < n) v = *(const ushort8v*)(f2bf + (size_t)gr * HH + k);
    *(ushort8v*)&T[lofs(r, k)] = v;
  }

  // --- gen preload, C-fragment layout, packed bf16 pairs ---
  unsigned genp[2][8][2];
#pragma unroll
  for (int tt = 0; tt < 2; ++tt)
#pragma unroll
    for (int cc = 0; cc < 8; ++cc)
#pragma unroll
      for (int gp = 0; gp < 2; ++gp) {
        int r0r = row0 + tt * 16 + quad * 4 + gp * 2;
        float v0 = (r0r < n) ? gen[(size_t)r0r * HH + cc * 16 + m] : 0.f;
        float v1 = (r0r + 1 < n) ? gen[(size_t)(r0r + 1) * HH + cc * 16 + m] : 0.f;
        genp[tt][cc][gp] = (unsigned)f2b(v0) | ((unsigned)f2b(v1) << 16);
      }

  __syncthreads();  // W1, W2 and all tiles visible

  bf16x8 af[2][4];
  f32x4 acc[2][8];
  float bv[8];

  // ---- stage 1: m = leaky(f2@Wm1+bm1) ----
#pragma unroll
  for (int cc = 0; cc < 8; ++cc) bv[cc] = bm1[cc * 16 + m];
  lds_afrags(T, m, quad, af);
  mfma_w32_lds(af, Wl[0], lane, acc);

  // prefetch W3 to regs (latency hides under stage 1 + barrier)
  uint4 pw3[4];
#pragma unroll
  for (int i = 0; i < 4; ++i) pw3[i] = ((const uint4*)Wp1p)[(wave * 4 + i) * 64 + lane];

  // capture f2 residual (C-fragment slots) BEFORE overwriting T
  unsigned f2res[2][8][2];
#pragma unroll
  for (int tt = 0; tt < 2; ++tt)
#pragma unroll
    for (int cc = 0; cc < 8; ++cc)
#pragma unroll
      for (int gp = 0; gp < 2; ++gp) {
        int lr = tt * 16 + quad * 4 + gp * 2, col = cc * 16 + m;
        f2res[tt][cc][gp] = (unsigned)T[lofs(lr, col)] |
                            ((unsigned)T[lofs(lr + 1, col)] << 16);
      }
  WAVE_SYNC();  // keep capture reads ahead of the overwrites below

#pragma unroll
  for (int tt = 0; tt < 2; ++tt)
#pragma unroll
    for (int cc = 0; cc < 8; ++cc) {
      int col = cc * 16 + m;
#pragma unroll
      for (int g = 0; g < 4; ++g)
        T[lofs(tt * 16 + quad * 4 + g, col)] = f2b(lrelu(acc[tt][cc][g] + bv[cc]));
    }
  __syncthreads();  // all waves done with W1 (buffer 0 free), tiles visible

  // write prefetched W3 into Wl[0]
#pragma unroll
  for (int i = 0; i < 4; ++i) *(uint4*)&Wl[0][(wave * 4 + i) * 512 + lane * 8] = pw3[i];

  // ---- stage 2: h3 = leaky(m@Wm2+bm2+f2res); p = 0.5*(h3+gen) ----
#pragma unroll
  for (int cc = 0; cc < 8; ++cc) bv[cc] = bm2[cc * 16 + m];
  lds_afrags(T, m, quad, af);
  mfma_w32_lds(af, Wl[1], lane, acc);

  // prefetch W4 to regs
  uint4 pw4[4];
#pragma unroll
  for (int i = 0; i < 4; ++i) pw4[i] = ((const uint4*)Wp2p)[(wave * 4 + i) * 64 + lane];

#pragma unroll
  for (int tt = 0; tt < 2; ++tt)
#pragma unroll
    for (int cc = 0; cc < 8; ++cc) {
      int col = cc * 16 + m;
#pragma unroll
      for (int g = 0; g < 4; ++g) {
        unsigned fr = f2res[tt][cc][g >> 1];
        float f2v = b2f((unsigned short)((g & 1) ? (fr >> 16) : (fr & 0xffffu)));
        float v = lrelu(acc[tt][cc][g] + bv[cc] + f2v);
        unsigned gp = genp[tt][cc][g >> 1];
        float gv = b2f((unsigned short)((g & 1) ? (gp >> 16) : (gp & 0xffffu)));
        T[lofs(tt * 16 + quad * 4 + g, col)] = f2b(0.5f * (v + gv));
      }
    }
  __syncthreads();  // W3 writes drained+visible; all waves done with W2

  // write prefetched W4 into Wl[1]
#pragma unroll
  for (int i = 0; i < 4; ++i) *(uint4*)&Wl[1][(wave * 4 + i) * 512 + lane * 8] = pw4[i];

  // ---- stage 3: q = leaky(p@Wp1+bp1) ----
#pragma unroll
  for (int cc = 0; cc < 8; ++cc) bv[cc] = bp1[cc * 16 + m];
  lds_afrags(T, m, quad, af);
  mfma_w32_lds(af, Wl[0], lane, acc);
#pragma unroll
  for (int tt = 0; tt < 2; ++tt)
#pragma unroll
    for (int cc = 0; cc < 8; ++cc) {
      int col = cc * 16 + m;
#pragma unroll
      for (int g = 0; g < 4; ++g)
        T[lofs(tt * 16 + quad * 4 + g, col)] = f2b(lrelu(acc[tt][cc][g] + bv[cc]));
    }
  __syncthreads();  // W4 writes drained+visible

  // ---- stage 4: out = leaky(q@Wp2+bp2) ----
#pragma unroll
  for (int cc = 0; cc < 8; ++cc) bv[cc] = bp2[cc * 16 + m];
  lds_afrags(T, m, quad, af);
  mfma_w32_lds(af, Wl[1], lane, acc);
#pragma unroll
  for (int tt = 0; tt < 2; ++tt)
#pragma unroll
    for (int cc = 0; cc < 8; ++cc) {
      int col = cc * 16 + m;
#pragma unroll
      for (int g = 0; g < 4; ++g) {
        int row = row0 + tt * 16 + quad * 4 + g;
        if (row < n) out[(size_t)row * HH + col] = lrelu(acc[tt][cc][g] + bv[cc]);
      }
    }
}

// ---------------- launcher ----------------

extern "C" void kernel_launch(void* const* d_in, const int* in_sizes, int n_in,
                              void* d_out, int out_size, void* d_ws, size_t ws_size,
                              hipStream_t stream) {
  const float* x   = (const float*)d_in[0];
  const int* ei    = (const int*)d_in[1];
  const float* gen = (const float*)d_in[2];
  const float* Wc1 = (const float*)d_in[3];
  const float* bc1 = (const float*)d_in[4];
  const float* Wc2 = (const float*)d_in[5];
  const float* bc2 = (const float*)d_in[6];
  const float* Wm1 = (const float*)d_in[7];
  const float* bm1 = (const float*)d_in[8];
  const float* Wm2 = (const float*)d_in[9];
  const float* bm2 = (const float*)d_in[10];
  const float* Wp1 = (const float*)d_in[11];
  const float* bp1 = (const float*)d_in[12];
  const float* Wp2 = (const float*)d_in[13];
  const float* bp2 = (const float*)d_in[14];

  const int N = in_sizes[0] / HH;
  const int E = in_sizes[1] / 2;
  const int* src = ei;
  const int* dst = ei + E;

  char* ws = (char*)d_ws;
  size_t off = 0;
  auto alloc = [&](size_t bytes) { void* p = ws + off; off += (bytes + 255) & ~(size_t)255; return p; };
  float* dinv            = (float*)alloc((size_t)N * 4);
  int*   rowptr          = (int*)  alloc((size_t)(N + 1) * 4);
  int*   cursor          = (int*)  alloc((size_t)N * 4);
  int*   bsum            = (int*)  alloc((size_t)64 * 4);
  int2*  csr             = (int2*) alloc((size_t)E * 8);
  unsigned short* h_bf   = (unsigned short*)alloc((size_t)N * HH * 2);
  unsigned short* t2_bf  = (unsigned short*)alloc((size_t)N * HH * 2);
  unsigned short* f2_bf  = (unsigned short*)alloc((size_t)N * HH * 2);
  float* f1_f32          = (float*)alloc((size_t)N * HH * 4);
  unsigned short* packed = (unsigned short*)alloc((size_t)6 * 16384 * 2);
  float* fOut = (float*)d_out;

  const int cblocks = (N + 255) / 256;    // 8 waves x 32 rows per block
  const int eblocks = (E + 255) / 256;
  const int ablocks = (N + 3) / 4;
  const int sblocks = (N + 1023) / 1024;  // <= 64 for N <= 65536

  // weight packing
  pack_kernel<<<dim3(64, 6), 256, 0, stream>>>(Wc1, Wc2, Wm1, Wm2, Wp1, Wp2, packed);

  // CSR build
  hipMemsetAsync(cursor, 0, (size_t)N * 4, stream);
  count_kernel<<<eblocks, 256, 0, stream>>>(dst, cursor, E);
  scan1_kernel<<<sblocks, 1024, 0, stream>>>(cursor, rowptr, bsum, dinv, N);
  scan2_kernel<<<1, 64, 0, stream>>>(bsum, sblocks, rowptr, N, E);
  scan3_kernel<<<sblocks, 1024, 0, stream>>>(rowptr, bsum, N);
  fill_kernel<<<eblocks, 256, 0, stream>>>(src, dst, rowptr, cursor, dinv, csr, E);

  // conv1: h_bf = bf16(x @ Wc1)
  gemm_conv<<<cblocks, 512, 0, stream>>>(x, packed + 0 * 16384, h_bf, N);
  // agg1: f1 = leaky(agg(h_bf)+self+bc1)  [fp32]
  agg_kernel<0, 0><<<ablocks, 256, 0, stream>>>(h_bf, rowptr, csr, dinv, bc1, nullptr, f1_f32, N);
  // conv2: t2 = bf16(f1 @ Wc2)
  gemm_conv<<<cblocks, 512, 0, stream>>>(f1_f32, packed + 1 * 16384, t2_bf, N);
  // agg2: f2 = leaky(agg(t2)+self+bc2+f1)  [bf16 — only consumed as bf16]
  agg_kernel<1, 1><<<ablocks, 256, 0, stream>>>(t2_bf, rowptr, csr, dinv, bc2, f1_f32, f2_bf, N);
  // fusedMLP: MLP + interp + proj -> d_out
  fusedMLP<<<cblocks, 512, 0, stream>>>(f2_bf,
                                        packed + 2 * 16384, packed + 3 * 16384,
                                        packed + 4 * 16384, packed + 5 * 16384,
                                        bm1, bm2, bp1, bp2, gen, fOut, N);
}

// Round 4
// 327.156 us; speedup vs baseline: 1.0436x; 1.0436x over previous
//
#include <hip/hip_runtime.h>
#include <cstdint>
#include <cstddef>

#define HH 128
#define SLOPE 0.01f

typedef __attribute__((ext_vector_type(8))) __bf16 bf16x8;
typedef __attribute__((ext_vector_type(8))) unsigned short ushort8v;
typedef __attribute__((ext_vector_type(4))) float f32x4;

__device__ __forceinline__ float lrelu(float x) { return x >= 0.f ? x : SLOPE * x; }
__device__ __forceinline__ unsigned short f2b(float f) {
  union { float f; unsigned u; } v; v.f = f;
  unsigned r = v.u + 0x7fffu + ((v.u >> 16) & 1u);  // round-to-nearest-even
  return (unsigned short)(r >> 16);
}
__device__ __forceinline__ float b2f(unsigned short u) {
  union { unsigned u; float f; } v; v.u = ((unsigned)u) << 16; return v.f;
}

// LDS tile layout with XOR swizzle: element (r,k) of a [rows]x128 bf16 tile lives at
// lofs(r,k). 16B chunks (8 ushorts) stay contiguous; chunk index ^= (r&15).
__device__ __forceinline__ int lofs(int r, int k) {
  return (r << 7) + ((((k >> 3) ^ r) & 15) << 3) + (k & 7);
}

// ---------------- CSR build ----------------

__global__ __launch_bounds__(256) void count_kernel(const int* __restrict__ dst,
                                                    int* __restrict__ cnt, int nE) {
  int e = blockIdx.x * 256 + threadIdx.x;
  if (e < nE) atomicAdd(&cnt[dst[e]], 1);
}

__global__ __launch_bounds__(1024) void scan1_kernel(int* __restrict__ cnt,
                                                     int* __restrict__ rowptr,
                                                     int* __restrict__ bsum,
                                                     float* __restrict__ dinv, int n) {
  __shared__ int wsum[16];
  const int tid = threadIdx.x;
  const int lane = tid & 63, wid = tid >> 6;
  int i = blockIdx.x * 1024 + tid;
  int v = (i < n) ? cnt[i] : 0;
  int x = v;
#pragma unroll
  for (int off = 1; off < 64; off <<= 1) {
    int y = __shfl_up(x, off, 64);
    if (lane >= off) x += y;
  }
  if (lane == 63) wsum[wid] = x;
  __syncthreads();
  if (tid == 0) {
    int s = 0;
#pragma unroll
    for (int w = 0; w < 16; ++w) { int t = wsum[w]; wsum[w] = s; s += t; }
    bsum[blockIdx.x] = s;
  }
  __syncthreads();
  if (i < n) {
    rowptr[i] = wsum[wid] + x - v;  // local exclusive
    dinv[i] = rsqrtf((float)v + 1.0f);
    cnt[i] = 0;
  }
}

__global__ __launch_bounds__(64) void scan2_kernel(int* __restrict__ bsum, int nb,
                                                   int* __restrict__ rowptr, int n, int E) {
  int lane = threadIdx.x;
  int v = (lane < nb) ? bsum[lane] : 0;
  int x = v;
#pragma unroll
  for (int off = 1; off < 64; off <<= 1) {
    int y = __shfl_up(x, off, 64);
    if (lane >= off) x += y;
  }
  if (lane < nb) bsum[lane] = x - v;  // exclusive
  if (lane == 0) rowptr[n] = E;
}

__global__ __launch_bounds__(1024) void scan3_kernel(int* __restrict__ rowptr,
                                                     const int* __restrict__ bsum, int n) {
  int i = blockIdx.x * 1024 + threadIdx.x;
  if (i < n) rowptr[i] += bsum[blockIdx.x];
}

// csr entry: .x = src node, .y = norm (float bits)
__global__ __launch_bounds__(256) void fill_kernel(const int* __restrict__ src,
                                                   const int* __restrict__ dst,
                                                   const int* __restrict__ rowptr,
                                                   int* __restrict__ cursor,
                                                   const float* __restrict__ dinv,
                                                   int2* __restrict__ csr, int nE) {
  int e = blockIdx.x * 256 + threadIdx.x;
  if (e >= nE) return;
  int d = dst[e], s = src[e];
  int pos = rowptr[d] + atomicAdd(&cursor[d], 1);
  int2 ent;
  ent.x = s;
  ent.y = __float_as_int(dinv[s] * dinv[d]);
  csr[pos] = ent;
}

// ---------------- weight pack: B-fragment order for mfma 16x16x32 ----------------
__global__ __launch_bounds__(256) void pack_kernel(const float* W0, const float* W1,
                                                   const float* W2, const float* W3,
                                                   const float* W4, const float* W5,
                                                   unsigned short* __restrict__ out) {
  const float* Ws[6] = {W0, W1, W2, W3, W4, W5};
  const float* W = Ws[blockIdx.y];
  int f = blockIdx.x * 256 + threadIdx.x;  // 0..16383
  int j = f & 7, L = (f >> 3) & 63, c = (f >> 9) & 7, t = f >> 12;
  int k = t * 32 + (L >> 4) * 8 + j;
  int n = c * 16 + (L & 15);
  out[(size_t)blockIdx.y * 16384 + f] = f2b(W[k * HH + n]);
}

// ---------------- shared device helpers ----------------

// 32-row (2 M-tile) MFMA stage; B-fragments from LDS (block-shared weight copy,
// linear layout: fragment f at bytes [f*1024 + lane*16]). ds_read_b128 of a
// contiguous 1KB fragment = throughput-bound, conflict-free.
__device__ __forceinline__ void mfma_w32_lds(const bf16x8 af[2][4],
                                             const unsigned short* __restrict__ Wl,
                                             int lane, f32x4 acc[2][8]) {
#pragma unroll
  for (int tt = 0; tt < 2; ++tt)
#pragma unroll
    for (int c = 0; c < 8; ++c) acc[tt][c] = (f32x4){0.f, 0.f, 0.f, 0.f};
#pragma unroll
  for (int t = 0; t < 4; ++t) {
    bf16x8 wf[8];
#pragma unroll
    for (int c = 0; c < 8; ++c) wf[c] = *(const bf16x8*)&Wl[(t * 8 + c) * 512 + lane * 8];
#pragma unroll
    for (int c = 0; c < 8; ++c)
#pragma unroll
      for (int tt = 0; tt < 2; ++tt)
        acc[tt][c] = __builtin_amdgcn_mfma_f32_16x16x32_bf16(af[tt][t], wf[c], acc[tt][c], 0, 0, 0);
  }
}

// A-fragments for both 16-row tiles from a 32-row swizzled LDS tile.
__device__ __forceinline__ void lds_afrags(const unsigned short* __restrict__ Tl,
                                           int m, int quad, bf16x8 af[2][4]) {
#pragma unroll
  for (int tt = 0; tt < 2; ++tt)
#pragma unroll
    for (int t = 0; t < 4; ++t)
      af[tt][t] = *(const bf16x8*)&Tl[lofs(tt * 16 + m, t * 32 + quad * 8)];
}

// ---------------- GEMM: A(fp32)[nrows,128] @ Wp -> bf16 out ----------------
// 4 waves/block, 32 rows/wave. Weights staged ONCE per block into 32KB LDS.
// __launch_bounds__(256,1): no VGPR cap (r3's (512,2) capped at 128 -> spills).

__global__ __launch_bounds__(256, 1) void gemm_conv(const float* __restrict__ A,
                                                    const unsigned short* __restrict__ Wp,
                                                    unsigned short* __restrict__ out, int nrows) {
  __shared__ __align__(16) unsigned short Wl[16384];
  const int tid = threadIdx.x;
  const int lane = tid & 63, wave = tid >> 6;
  const int row0 = blockIdx.x * 128 + wave * 32;
  const int m = lane & 15, quad = lane >> 4;

  // stage weights: each wave copies 8KB (fragments wave*8 .. wave*8+7)
  uint4 pw[8];
#pragma unroll
  for (int i = 0; i < 8; ++i) pw[i] = ((const uint4*)Wp)[(wave * 8 + i) * 64 + lane];
#pragma unroll
  for (int i = 0; i < 8; ++i) *(uint4*)&Wl[(wave * 8 + i) * 512 + lane * 8] = pw[i];

  // A fragments straight from global fp32, converted in-register
  bf16x8 af[2][4];
#pragma unroll
  for (int tt = 0; tt < 2; ++tt) {
    const int gr = row0 + tt * 16 + m;
    const bool rok = gr < nrows;
    const float* Arow = A + (size_t)gr * HH;
#pragma unroll
    for (int t = 0; t < 4; ++t) {
      const int k = t * 32 + quad * 8;
      float4 lo = make_float4(0.f, 0.f, 0.f, 0.f), hi = lo;
      if (rok) {
        lo = *(const float4*)(Arow + k);
        hi = *(const float4*)(Arow + k + 4);
      }
      union { ushort8v u; bf16x8 b; } cv;
      cv.u[0] = f2b(lo.x); cv.u[1] = f2b(lo.y); cv.u[2] = f2b(lo.z); cv.u[3] = f2b(lo.w);
      cv.u[4] = f2b(hi.x); cv.u[5] = f2b(hi.y); cv.u[6] = f2b(hi.z); cv.u[7] = f2b(hi.w);
      af[tt][t] = cv.b;
    }
  }

  __syncthreads();  // weights visible to all waves

  f32x4 acc[2][8];
  mfma_w32_lds(af, Wl, lane, acc);

#pragma unroll
  for (int tt = 0; tt < 2; ++tt)
#pragma unroll
    for (int c = 0; c < 8; ++c) {
      int col = c * 16 + m;
#pragma unroll
      for (int g = 0; g < 4; ++g) {
        int row = row0 + tt * 16 + quad * 4 + g;
        if (row < nrows) out[(size_t)row * HH + col] = f2b(acc[tt][c][g]);
      }
    }
}

// ---------------- agg: one wave per node ----------------
// out = leaky(sum norm*h[src] + self*dinv^2 + bias (+res fp32)); fp32 or bf16 out.

template <int RES, int OUTBF>
__global__ __launch_bounds__(256) void agg_kernel(const unsigned short* __restrict__ h,
                                                  const int* __restrict__ rowptr,
                                                  const int2* __restrict__ csr,
                                                  const float* __restrict__ dinv,
                                                  const float* __restrict__ bias,
                                                  const float* __restrict__ res,
                                                  void* __restrict__ outv, int n) {
  int node = blockIdx.x * 4 + (threadIdx.x >> 6);
  if (node >= n) return;
  int lane = threadIdx.x & 63;
  int c = lane << 1;
  int j = rowptr[node], end = rowptr[node + 1];
  float ax = 0.f, ay = 0.f;
  // 8-deep unroll: 8 outstanding gather loads per lane
  for (; j + 8 <= end; j += 8) {
    int2 e[8];
    ushort2 r[8];
#pragma unroll
    for (int q = 0; q < 8; ++q) e[q] = csr[j + q];
#pragma unroll
    for (int q = 0; q < 8; ++q) r[q] = *(const ushort2*)(h + (size_t)e[q].x * HH + c);
#pragma unroll
    for (int q = 0; q < 8; ++q) {
      float nv = __int_as_float(e[q].y);
      ax = fmaf(b2f(r[q].x), nv, ax); ay = fmaf(b2f(r[q].y), nv, ay);
    }
  }
  for (; j + 2 <= end; j += 2) {
    int2 e0 = csr[j], e1 = csr[j + 1];
    ushort2 r0 = *(const ushort2*)(h + (size_t)e0.x * HH + c);
    ushort2 r1 = *(const ushort2*)(h + (size_t)e1.x * HH + c);
    float n0 = __int_as_float(e0.y), n1 = __int_as_float(e1.y);
    ax = fmaf(b2f(r0.x), n0, ax); ay = fmaf(b2f(r0.y), n0, ay);
    ax = fmaf(b2f(r1.x), n1, ax); ay = fmaf(b2f(r1.y), n1, ay);
  }
  if (j < end) {
    int2 e0 = csr[j];
    float n0 = __int_as_float(e0.y);
    ushort2 r0 = *(const ushort2*)(h + (size_t)e0.x * HH + c);
    ax = fmaf(b2f(r0.x), n0, ax); ay = fmaf(b2f(r0.y), n0, ay);
  }
  float di = dinv[node], d2 = di * di;
  ushort2 hs = *(const ushort2*)(h + (size_t)node * HH + c);
  float2 b = *(const float2*)(bias + c);
  float ox = ax + b2f(hs.x) * d2 + b.x;
  float oy = ay + b2f(hs.y) * d2 + b.y;
  if (RES) {
    float2 r = *(const float2*)(res + (size_t)node * HH + c);
    ox += r.x; oy += r.y;
  }
  ox = lrelu(ox); oy = lrelu(oy);
  if (OUTBF) {
    ushort2 o; o.x = f2b(ox); o.y = f2b(oy);
    *(ushort2*)((unsigned short*)outv + (size_t)node * HH + c) = o;
  } else {
    *(float2*)((float*)outv + (size_t)node * HH + c) = make_float2(ox, oy);
  }
}

// ---------------- fusedMLP: 4-GEMM chain, 4 waves/block, LDS-shared weights ----
// 128 rows/block (4 waves x 32). Weights ping-pong through 2x32KB LDS buffers;
// W3/W4 prefetched to regs during stage 1/2 compute and ds_written after the
// barrier frees the buffer. Each wave owns TWO 8KB tile buffers (Ta: f2 then p;
// Tb: m then q) so no register capture of the residual is needed (r3's spill
// source). All cross-lane LDS RAW pairs are separated by a __syncthreads.
// stage 1:  m  = leaky(f2@Wm1+bm1)                     Ta -> Tb
// stage 2:  h3 = leaky(m@Wm2+bm2 + f2); p=0.5*(h3+gen) Tb(+Ta res) -> Ta
// stage 3:  q  = leaky(p@Wp1+bp1)                      Ta -> Tb
// stage 4:  out= leaky(q@Wp2+bp2)                      Tb -> fp32 global

__global__ __launch_bounds__(256, 1) void fusedMLP(const unsigned short* __restrict__ f2bf,
                                                   const unsigned short* __restrict__ Wm1p,
                                                   const unsigned short* __restrict__ Wm2p,
                                                   const unsigned short* __restrict__ Wp1p,
                                                   const unsigned short* __restrict__ Wp2p,
                                                   const float* __restrict__ bm1,
                                                   const float* __restrict__ bm2,
                                                   const float* __restrict__ bp1,
                                                   const float* __restrict__ bp2,
                                                   const float* __restrict__ gen,
                                                   float* __restrict__ out, int n) {
  __shared__ __align__(16) unsigned short Wl[2][16384];   // 2 x 32KB weight ping-pong
  __shared__ __align__(16) unsigned short Ta[4][32 * HH]; // 4 x 8KB wave tiles
  __shared__ __align__(16) unsigned short Tb[4][32 * HH]; // 4 x 8KB wave tiles
  const int tid = threadIdx.x;
  const int lane = tid & 63, wave = tid >> 6;
  const int row0 = blockIdx.x * 128 + wave * 32;
  const int m = lane & 15, quad = lane >> 4;
  unsigned short* TA = Ta[wave];
  unsigned short* TB = Tb[wave];

  // --- prologue: stage W1 -> Wl[0], W2 -> Wl[1] (each wave 8 fragments per buf) ---
  {
    uint4 pw[16];
#pragma unroll
    for (int b = 0; b < 2; ++b) {
      const unsigned short* Ws = b ? Wm2p : Wm1p;
#pragma unroll
      for (int i = 0; i < 8; ++i)
        pw[b * 8 + i] = ((const uint4*)Ws)[(wave * 8 + i) * 64 + lane];
    }
#pragma unroll
    for (int b = 0; b < 2; ++b)
#pragma unroll
      for (int i = 0; i < 8; ++i)
        *(uint4*)&Wl[b][(wave * 8 + i) * 512 + lane * 8] = pw[b * 8 + i];
  }

  // --- stage f2 tile into Ta (swizzled): 8 x 16B per lane ---
#pragma unroll
  for (int i = 0; i < 8; ++i) {
    int idx = i * 64 + lane;            // 16B-chunk id 0..511
    int r = idx >> 4, k = (idx & 15) << 3;
    int gr = row0 + r;
    ushort8v v = {0, 0, 0, 0, 0, 0, 0, 0};
    if (gr < n) v = *(const ushort8v*)(f2bf + (size_t)gr * HH + k);
    *(ushort8v*)&TA[lofs(r, k)] = v;
  }

  // --- gen preload, C-fragment layout, packed bf16 pairs (32 VGPR) ---
  unsigned genp[2][8][2];
#pragma unroll
  for (int tt = 0; tt < 2; ++tt)
#pragma unroll
    for (int cc = 0; cc < 8; ++cc)
#pragma unroll
      for (int gp = 0; gp < 2; ++gp) {
        int r0r = row0 + tt * 16 + quad * 4 + gp * 2;
        float v0 = (r0r < n) ? gen[(size_t)r0r * HH + cc * 16 + m] : 0.f;
        float v1 = (r0r + 1 < n) ? gen[(size_t)(r0r + 1) * HH + cc * 16 + m] : 0.f;
        genp[tt][cc][gp] = (unsigned)f2b(v0) | ((unsigned)f2b(v1) << 16);
      }

  __syncthreads();  // barrier A: W1, W2, tiles visible

  bf16x8 af[2][4];
  f32x4 acc[2][8];
  float bv[8];

  // ---- stage 1: m = leaky(f2@Wm1+bm1), Ta -> Tb ----
#pragma unroll
  for (int cc = 0; cc < 8; ++cc) bv[cc] = bm1[cc * 16 + m];
  lds_afrags(TA, m, quad, af);
  mfma_w32_lds(af, Wl[0], lane, acc);

  // prefetch W3 to regs (latency hides under stage-1 compute)
  uint4 pw3[8];
#pragma unroll
  for (int i = 0; i < 8; ++i) pw3[i] = ((const uint4*)Wp1p)[(wave * 8 + i) * 64 + lane];

#pragma unroll
  for (int tt = 0; tt < 2; ++tt)
#pragma unroll
    for (int cc = 0; cc < 8; ++cc) {
      int col = cc * 16 + m;
#pragma unroll
      for (int g = 0; g < 4; ++g)
        TB[lofs(tt * 16 + quad * 4 + g, col)] = f2b(lrelu(acc[tt][cc][g] + bv[cc]));
    }
  __syncthreads();  // barrier B: all waves done with W1; Tb writes visible

  // write prefetched W3 into Wl[0]
#pragma unroll
  for (int i = 0; i < 8; ++i) *(uint4*)&Wl[0][(wave * 8 + i) * 512 + lane * 8] = pw3[i];

  // ---- stage 2: h3 = leaky(m@Wm2+bm2+f2); p = 0.5*(h3+gen), Tb(+Ta) -> Ta ----
#pragma unroll
  for (int cc = 0; cc < 8; ++cc) bv[cc] = bm2[cc * 16 + m];
  lds_afrags(TB, m, quad, af);
  mfma_w32_lds(af, Wl[1], lane, acc);

  // prefetch W4 to regs
  uint4 pw4[8];
#pragma unroll
  for (int i = 0; i < 8; ++i) pw4[i] = ((const uint4*)Wp2p)[(wave * 8 + i) * 64 + lane];

#pragma unroll
  for (int tt = 0; tt < 2; ++tt)
#pragma unroll
    for (int cc = 0; cc < 8; ++cc) {
      int col = cc * 16 + m;
#pragma unroll
      for (int g = 0; g < 4; ++g) {
        int lr = tt * 16 + quad * 4 + g;
        float f2v = b2f(TA[lofs(lr, col)]);   // same-lane slot: read, then overwrite
        float v = lrelu(acc[tt][cc][g] + bv[cc] + f2v);
        unsigned gp = genp[tt][cc][g >> 1];
        float gv = b2f((unsigned short)((g & 1) ? (gp >> 16) : (gp & 0xffffu)));
        TA[lofs(lr, col)] = f2b(0.5f * (v + gv));
      }
    }
  __syncthreads();  // barrier C: W3 writes visible; all waves done with W2

  // write prefetched W4 into Wl[1]
#pragma unroll
  for (int i = 0; i < 8; ++i) *(uint4*)&Wl[1][(wave * 8 + i) * 512 + lane * 8] = pw4[i];

  // ---- stage 3: q = leaky(p@Wp1+bp1), Ta -> Tb ----
#pragma unroll
  for (int cc = 0; cc < 8; ++cc) bv[cc] = bp1[cc * 16 + m];
  lds_afrags(TA, m, quad, af);
  mfma_w32_lds(af, Wl[0], lane, acc);
#pragma unroll
  for (int tt = 0; tt < 2; ++tt)
#pragma unroll
    for (int cc = 0; cc < 8; ++cc) {
      int col = cc * 16 + m;
#pragma unroll
      for (int g = 0; g < 4; ++g)
        TB[lofs(tt * 16 + quad * 4 + g, col)] = f2b(lrelu(acc[tt][cc][g] + bv[cc]));
    }
  __syncthreads();  // barrier D: W4 writes visible; Tb writes visible

  // ---- stage 4: out = leaky(q@Wp2+bp2), Tb -> global ----
#pragma unroll
  for (int cc = 0; cc < 8; ++cc) bv[cc] = bp2[cc * 16 + m];
  lds_afrags(TB, m, quad, af);
  mfma_w32_lds(af, Wl[1], lane, acc);
#pragma unroll
  for (int tt = 0; tt < 2; ++tt)
#pragma unroll
    for (int cc = 0; cc < 8; ++cc) {
      int col = cc * 16 + m;
#pragma unroll
      for (int g = 0; g < 4; ++g) {
        int row = row0 + tt * 16 + quad * 4 + g;
        if (row < n) out[(size_t)row * HH + col] = lrelu(acc[tt][cc][g] + bv[cc]);
      }
    }
}

// ---------------- launcher ----------------

extern "C" void kernel_launch(void* const* d_in, const int* in_sizes, int n_in,
                              void* d_out, int out_size, void* d_ws, size_t ws_size,
                              hipStream_t stream) {
  const float* x   = (const float*)d_in[0];
  const int* ei    = (const int*)d_in[1];
  const float* gen = (const float*)d_in[2];
  const float* Wc1 = (const float*)d_in[3];
  const float* bc1 = (const float*)d_in[4];
  const float* Wc2 = (const float*)d_in[5];
  const float* bc2 = (const float*)d_in[6];
  const float* Wm1 = (const float*)d_in[7];
  const float* bm1 = (const float*)d_in[8];
  const float* Wm2 = (const float*)d_in[9];
  const float* bm2 = (const float*)d_in[10];
  const float* Wp1 = (const float*)d_in[11];
  const float* bp1 = (const float*)d_in[12];
  const float* Wp2 = (const float*)d_in[13];
  const float* bp2 = (const float*)d_in[14];

  const int N = in_sizes[0] / HH;
  const int E = in_sizes[1] / 2;
  const int* src = ei;
  const int* dst = ei + E;

  char* ws = (char*)d_ws;
  size_t off = 0;
  auto alloc = [&](size_t bytes) { void* p = ws + off; off += (bytes + 255) & ~(size_t)255; return p; };
  float* dinv            = (float*)alloc((size_t)N * 4);
  int*   rowptr          = (int*)  alloc((size_t)(N + 1) * 4);
  int*   cursor          = (int*)  alloc((size_t)N * 4);
  int*   bsum            = (int*)  alloc((size_t)64 * 4);
  int2*  csr             = (int2*) alloc((size_t)E * 8);
  unsigned short* h_bf   = (unsigned short*)alloc((size_t)N * HH * 2);
  unsigned short* t2_bf  = (unsigned short*)alloc((size_t)N * HH * 2);
  unsigned short* f2_bf  = (unsigned short*)alloc((size_t)N * HH * 2);
  float* f1_f32          = (float*)alloc((size_t)N * HH * 4);
  unsigned short* packed = (unsigned short*)alloc((size_t)6 * 16384 * 2);
  float* fOut = (float*)d_out;

  const int cblocks = (N + 127) / 128;    // 4 waves x 32 rows per block
  const int eblocks = (E + 255) / 256;
  const int ablocks = (N + 3) / 4;
  const int sblocks = (N + 1023) / 1024;  // <= 64 for N <= 65536

  // weight packing
  pack_kernel<<<dim3(64, 6), 256, 0, stream>>>(Wc1, Wc2, Wm1, Wm2, Wp1, Wp2, packed);

  // CSR build
  hipMemsetAsync(cursor, 0, (size_t)N * 4, stream);
  count_kernel<<<eblocks, 256, 0, stream>>>(dst, cursor, E);
  scan1_kernel<<<sblocks, 1024, 0, stream>>>(cursor, rowptr, bsum, dinv, N);
  scan2_kernel<<<1, 64, 0, stream>>>(bsum, sblocks, rowptr, N, E);
  scan3_kernel<<<sblocks, 1024, 0, stream>>>(rowptr, bsum, N);
  fill_kernel<<<eblocks, 256, 0, stream>>>(src, dst, rowptr, cursor, dinv, csr, E);

  // conv1: h_bf = bf16(x @ Wc1)
  gemm_conv<<<cblocks, 256, 0, stream>>>(x, packed + 0 * 16384, h_bf, N);
  // agg1: f1 = leaky(agg(h_bf)+self+bc1)  [fp32]
  agg_kernel<0, 0><<<ablocks, 256, 0, stream>>>(h_bf, rowptr, csr, dinv, bc1, nullptr, f1_f32, N);
  // conv2: t2 = bf16(f1 @ Wc2)
  gemm_conv<<<cblocks, 256, 0, stream>>>(f1_f32, packed + 1 * 16384, t2_bf, N);
  // agg2: f2 = leaky(agg(t2)+self+bc2+f1)  [bf16 — only consumed as bf16]
  agg_kernel<1, 1><<<ablocks, 256, 0, stream>>>(t2_bf, rowptr, csr, dinv, bc2, f1_f32, f2_bf, N);
  // fusedMLP: MLP + interp + proj -> d_out
  fusedMLP<<<cblocks, 256, 0, stream>>>(f2_bf,
                                        packed + 2 * 16384, packed + 3 * 16384,
                                        packed + 4 * 16384, packed + 5 * 16384,
                                        bm1, bm2, bp1, bp2, gen, fOut, N);
}

// Round 6
// 300.338 us; speedup vs baseline: 1.1368x; 1.0893x over previous
//
#include <hip/hip_runtime.h>
#include <cstdint>
#include <cstddef>

#define HH 128
#define SLOPE 0.01f

typedef __attribute__((ext_vector_type(8))) __bf16 bf16x8;
typedef __attribute__((ext_vector_type(8))) unsigned short ushort8v;
typedef __attribute__((ext_vector_type(4))) float f32x4;

__device__ __forceinline__ float lrelu(float x) { return x >= 0.f ? x : SLOPE * x; }
__device__ __forceinline__ unsigned short f2b(float f) {
  union { float f; unsigned u; } v; v.f = f;
  unsigned r = v.u + 0x7fffu + ((v.u >> 16) & 1u);  // round-to-nearest-even
  return (unsigned short)(r >> 16);
}
__device__ __forceinline__ float b2f(unsigned short u) {
  union { unsigned u; float f; } v; v.u = ((unsigned)u) << 16; return v.f;
}

// LDS tile layout with XOR swizzle: element (r,k) of a [rows]x128 bf16 tile lives at
// lofs(r,k). 16B chunks (8 ushorts) stay contiguous; chunk index ^= (r&15).
__device__ __forceinline__ int lofs(int r, int k) {
  return (r << 7) + ((((k >> 3) ^ r) & 15) << 3) + (k & 7);
}

// Single-wave LDS write->read sync: wave is lockstep (one PC); lgkmcnt(0) drain +
// compiler fence is sufficient. No s_barrier, no vmcnt(0) drain.
#define WAVE_SYNC() asm volatile("s_waitcnt lgkmcnt(0)" ::: "memory")

// ---------------- CSR build ----------------

__global__ __launch_bounds__(256) void count_kernel(const int* __restrict__ dst,
                                                    int* __restrict__ cnt, int nE) {
  int e = blockIdx.x * 256 + threadIdx.x;
  if (e < nE) atomicAdd(&cnt[dst[e]], 1);
}

__global__ __launch_bounds__(1024) void scan1_kernel(int* __restrict__ cnt,
                                                     int* __restrict__ rowptr,
                                                     int* __restrict__ bsum,
                                                     float* __restrict__ dinv, int n) {
  __shared__ int wsum[16];
  const int tid = threadIdx.x;
  const int lane = tid & 63, wid = tid >> 6;
  int i = blockIdx.x * 1024 + tid;
  int v = (i < n) ? cnt[i] : 0;
  int x = v;
#pragma unroll
  for (int off = 1; off < 64; off <<= 1) {
    int y = __shfl_up(x, off, 64);
    if (lane >= off) x += y;
  }
  if (lane == 63) wsum[wid] = x;
  __syncthreads();
  if (tid == 0) {
    int s = 0;
#pragma unroll
    for (int w = 0; w < 16; ++w) { int t = wsum[w]; wsum[w] = s; s += t; }
    bsum[blockIdx.x] = s;
  }
  __syncthreads();
  if (i < n) {
    rowptr[i] = wsum[wid] + x - v;  // local exclusive
    dinv[i] = rsqrtf((float)v + 1.0f);
    cnt[i] = 0;
  }
}

__global__ __launch_bounds__(64) void scan2_kernel(int* __restrict__ bsum, int nb,
                                                   int* __restrict__ rowptr, int n, int E) {
  int lane = threadIdx.x;
  int v = (lane < nb) ? bsum[lane] : 0;
  int x = v;
#pragma unroll
  for (int off = 1; off < 64; off <<= 1) {
    int y = __shfl_up(x, off, 64);
    if (lane >= off) x += y;
  }
  if (lane < nb) bsum[lane] = x - v;  // exclusive
  if (lane == 0) rowptr[n] = E;
}

__global__ __launch_bounds__(1024) void scan3_kernel(int* __restrict__ rowptr,
                                                     const int* __restrict__ bsum, int n) {
  int i = blockIdx.x * 1024 + threadIdx.x;
  if (i < n) rowptr[i] += bsum[blockIdx.x];
}

// csr entry: .x = src node, .y = norm (float bits)
__global__ __launch_bounds__(256) void fill_kernel(const int* __restrict__ src,
                                                   const int* __restrict__ dst,
                                                   const int* __restrict__ rowptr,
                                                   int* __restrict__ cursor,
                                                   const float* __restrict__ dinv,
                                                   int2* __restrict__ csr, int nE) {
  int e = blockIdx.x * 256 + threadIdx.x;
  if (e >= nE) return;
  int d = dst[e], s = src[e];
  int pos = rowptr[d] + atomicAdd(&cursor[d], 1);
  int2 ent;
  ent.x = s;
  ent.y = __float_as_int(dinv[s] * dinv[d]);
  csr[pos] = ent;
}

// ---------------- weight pack: B-fragment order for mfma 16x16x32 ----------------
__global__ __launch_bounds__(256) void pack_kernel(const float* W0, const float* W1,
                                                   const float* W2, const float* W3,
                                                   const float* W4, const float* W5,
                                                   unsigned short* __restrict__ out) {
  const float* Ws[6] = {W0, W1, W2, W3, W4, W5};
  const float* W = Ws[blockIdx.y];
  int f = blockIdx.x * 256 + threadIdx.x;  // 0..16383
  int j = f & 7, L = (f >> 3) & 63, c = (f >> 9) & 7, t = f >> 12;
  int k = t * 32 + (L >> 4) * 8 + j;
  int n = c * 16 + (L & 15);
  out[(size_t)blockIdx.y * 16384 + f] = f2b(W[k * HH + n]);
}

// ---------------- shared device helpers ----------------

// 16-row MFMA stage; B-fragments streamed from global (L2-hot) in 8-deep batches.
__device__ __forceinline__ void mfma_stage(const bf16x8 af[4], const bf16x8* __restrict__ Wf,
                                           int lane, f32x4 acc[8]) {
#pragma unroll
  for (int c = 0; c < 8; ++c) acc[c] = (f32x4){0.f, 0.f, 0.f, 0.f};
#pragma unroll
  for (int t = 0; t < 4; ++t) {
    bf16x8 wf[8];
#pragma unroll
    for (int c = 0; c < 8; ++c) wf[c] = Wf[(t * 8 + c) * 64 + lane];
#pragma unroll
    for (int c = 0; c < 8; ++c)
      acc[c] = __builtin_amdgcn_mfma_f32_16x16x32_bf16(af[t], wf[c], acc[c], 0, 0, 0);
  }
}

// A-fragments from a 16-row swizzled LDS tile (arow = lane&15).
__device__ __forceinline__ void lds_afrags16(const unsigned short* __restrict__ Tl,
                                             int m, int quad, bf16x8 af[4]) {
#pragma unroll
  for (int t = 0; t < 4; ++t)
    af[t] = *(const bf16x8*)&Tl[lofs(m, t * 32 + quad * 8)];
}

// ---------------- GEMM: A(fp32)[nrows,128] @ Wp -> bf16 out ----------------
// 4 independent waves per 256-thr block, 16 rows/wave, no barriers, no LDS.
// A fragments load straight from the lane's own fp32 row (32B contiguous).

__global__ __launch_bounds__(256, 1) void gemm_conv(const float* __restrict__ A,
                                                    const unsigned short* __restrict__ Wp,
                                                    unsigned short* __restrict__ out, int nrows) {
  const int tid = threadIdx.x;
  const int lane = tid & 63, wave = tid >> 6;
  const int row0 = blockIdx.x * 64 + wave * 16;
  const int m = lane & 15, quad = lane >> 4;
  const int gr = row0 + m;
  const bool rok = gr < nrows;
  const float* Arow = A + (size_t)gr * HH;

  bf16x8 af[4];
#pragma unroll
  for (int t = 0; t < 4; ++t) {
    const int k = t * 32 + quad * 8;
    float4 lo = make_float4(0.f, 0.f, 0.f, 0.f), hi = lo;
    if (rok) {
      lo = *(const float4*)(Arow + k);
      hi = *(const float4*)(Arow + k + 4);
    }
    union { ushort8v u; bf16x8 b; } cv;
    cv.u[0] = f2b(lo.x); cv.u[1] = f2b(lo.y); cv.u[2] = f2b(lo.z); cv.u[3] = f2b(lo.w);
    cv.u[4] = f2b(hi.x); cv.u[5] = f2b(hi.y); cv.u[6] = f2b(hi.z); cv.u[7] = f2b(hi.w);
    af[t] = cv.b;
  }

  f32x4 acc[8];
  mfma_stage(af, (const bf16x8*)Wp, lane, acc);

#pragma unroll
  for (int c = 0; c < 8; ++c) {
    int col = c * 16 + m;
#pragma unroll
    for (int g = 0; g < 4; ++g) {
      int row = row0 + quad * 4 + g;
      if (row < nrows) out[(size_t)row * HH + col] = f2b(acc[c][g]);
    }
  }
}

// ---------------- agg: one wave per node ----------------
// out = leaky(sum norm*h[src] + self*dinv^2 + bias (+res fp32)); fp32 or bf16 out.

template <int RES, int OUTBF>
__global__ __launch_bounds__(256) void agg_kernel(const unsigned short* __restrict__ h,
                                                  const int* __restrict__ rowptr,
                                                  const int2* __restrict__ csr,
                                                  const float* __restrict__ dinv,
                                                  const float* __restrict__ bias,
                                                  const float* __restrict__ res,
                                                  void* __restrict__ outv, int n) {
  int node = blockIdx.x * 4 + (threadIdx.x >> 6);
  if (node >= n) return;
  int lane = threadIdx.x & 63;
  int c = lane << 1;
  int j = rowptr[node], end = rowptr[node + 1];
  float ax = 0.f, ay = 0.f;
  // 8-deep unroll: 8 outstanding gather loads per lane
  for (; j + 8 <= end; j += 8) {
    int2 e[8];
    ushort2 r[8];
#pragma unroll
    for (int q = 0; q < 8; ++q) e[q] = csr[j + q];
#pragma unroll
    for (int q = 0; q < 8; ++q) r[q] = *(const ushort2*)(h + (size_t)e[q].x * HH + c);
#pragma unroll
    for (int q = 0; q < 8; ++q) {
      float nv = __int_as_float(e[q].y);
      ax = fmaf(b2f(r[q].x), nv, ax); ay = fmaf(b2f(r[q].y), nv, ay);
    }
  }
  for (; j + 2 <= end; j += 2) {
    int2 e0 = csr[j], e1 = csr[j + 1];
    ushort2 r0 = *(const ushort2*)(h + (size_t)e0.x * HH + c);
    ushort2 r1 = *(const ushort2*)(h + (size_t)e1.x * HH + c);
    float n0 = __int_as_float(e0.y), n1 = __int_as_float(e1.y);
    ax = fmaf(b2f(r0.x), n0, ax); ay = fmaf(b2f(r0.y), n0, ay);
    ax = fmaf(b2f(r1.x), n1, ax); ay = fmaf(b2f(r1.y), n1, ay);
  }
  if (j < end) {
    int2 e0 = csr[j];
    float n0 = __int_as_float(e0.y);
    ushort2 r0 = *(const ushort2*)(h + (size_t)e0.x * HH + c);
    ax = fmaf(b2f(r0.x), n0, ax); ay = fmaf(b2f(r0.y), n0, ay);
  }
  float di = dinv[node], d2 = di * di;
  ushort2 hs = *(const ushort2*)(h + (size_t)node * HH + c);
  float2 b = *(const float2*)(bias + c);
  float ox = ax + b2f(hs.x) * d2 + b.x;
  float oy = ay + b2f(hs.y) * d2 + b.y;
  if (RES) {
    float2 r = *(const float2*)(res + (size_t)node * HH + c);
    ox += r.x; oy += r.y;
  }
  ox = lrelu(ox); oy = lrelu(oy);
  if (OUTBF) {
    ushort2 o; o.x = f2b(ox); o.y = f2b(oy);
    *(ushort2*)((unsigned short*)outv + (size_t)node * HH + c) = o;
  } else {
    *(float2*)((float*)outv + (size_t)node * HH + c) = make_float2(ox, oy);
  }
}

// ---------------- fusedMLP: 4-GEMM chain, 4 independent waves/block ----------------
// 16 rows/wave, zero block barriers. All global reads are VECTOR loads:
//   f2   -> Ta (4 x 16B/lane), gen -> 16 bf16-packed regs (8 x float4/lane),
//   all 4 biases -> BI (2 x float4/lane). No scalar global loads anywhere.
// Tb does double duty in stage 2: A-frags (m) are consumed into regs, then gen
// is ds_written into Tb and read back at C-slots for the interp epilogue.
// LDS = 4 waves x (Ta 4KB + Tb 4KB + BI 2KB) = 40KB/block -> 4 blocks/CU.
// stage 1:  m  = leaky(f2@Wm1+bm1)                     Ta -> Tb
// stage 2:  h3 = leaky(m@Wm2+bm2 + f2); p=0.5*(h3+gen) Tb,Ta -> Ta
// stage 3:  q  = leaky(p@Wp1+bp1)                      Ta -> Tb
// stage 4:  out= leaky(q@Wp2+bp2)                      Tb -> fp32 global

__global__ __launch_bounds__(256, 1) void fusedMLP(const unsigned short* __restrict__ f2bf,
                                                   const unsigned short* __restrict__ Wm1p,
                                                   const unsigned short* __restrict__ Wm2p,
                                                   const unsigned short* __restrict__ Wp1p,
                                                   const unsigned short* __restrict__ Wp2p,
                                                   const float* __restrict__ bm1,
                                                   const float* __restrict__ bm2,
                                                   const float* __restrict__ bp1,
                                                   const float* __restrict__ bp2,
                                                   const float* __restrict__ gen,
                                                   float* __restrict__ out, int n) {
  __shared__ __align__(16) unsigned short Ta[4][16 * HH];
  __shared__ __align__(16) unsigned short Tb[4][16 * HH];
  __shared__ __align__(16) float Bi[4][4 * HH];
  const int tid = threadIdx.x;
  const int lane = tid & 63, wave = tid >> 6;
  const int row0 = blockIdx.x * 64 + wave * 16;
  const int m = lane & 15, quad = lane >> 4;
  unsigned short* TA = Ta[wave];
  unsigned short* TB = Tb[wave];
  float* BI = Bi[wave];

  // --- f2 tile -> TA (swizzled), 4 x 16B per lane ---
#pragma unroll
  for (int i = 0; i < 4; ++i) {
    int idx = i * 64 + lane;            // 16B-chunk id 0..255
    int r = idx >> 4, k = (idx & 15) << 3;
    int gr = row0 + r;
    ushort8v v = {0, 0, 0, 0, 0, 0, 0, 0};
    if (gr < n) v = *(const ushort8v*)(f2bf + (size_t)gr * HH + k);
    *(ushort8v*)&TA[lofs(r, k)] = v;
  }

  // --- gen -> bf16 regs in staging-chunk layout (held until stage 2) ---
  ushort4 genb[8];
#pragma unroll
  for (int i = 0; i < 8; ++i) {
    int idx = i * 64 + lane;            // float4-chunk id 0..511
    int r = idx >> 5, c4 = (idx & 31) << 2;
    int gr = row0 + r;
    float4 v = make_float4(0.f, 0.f, 0.f, 0.f);
    if (gr < n) v = *(const float4*)(gen + (size_t)gr * HH + c4);
    genb[i].x = f2b(v.x); genb[i].y = f2b(v.y); genb[i].z = f2b(v.z); genb[i].w = f2b(v.w);
  }

  // --- all 4 biases -> BI, 2 x float4 per lane; layout [mat*128 + col] ---
  {
    const float* b01 = (lane < 32) ? bm1 : bm2;
    const float* b23 = (lane < 32) ? bp1 : bp2;
    int col = (lane & 31) << 2;
    float4 v0 = *(const float4*)(b01 + col);
    float4 v1 = *(const float4*)(b23 + col);
    *(float4*)&BI[lane * 4] = v0;         // lane<32 -> bm1, else bm2
    *(float4*)&BI[256 + lane * 4] = v1;   // lane<32 -> bp1, else bp2
  }
  WAVE_SYNC();  // LDS staging visible cross-lane (within wave)

  bf16x8 af[4];
  f32x4 acc[8];
  float bv[8];

  // ---- stage 1: m = leaky(f2@Wm1+bm1), Ta -> Tb ----
#pragma unroll
  for (int cc = 0; cc < 8; ++cc) bv[cc] = BI[cc * 16 + m];
  lds_afrags16(TA, m, quad, af);
  mfma_stage(af, (const bf16x8*)Wm1p, lane, acc);
#pragma unroll
  for (int cc = 0; cc < 8; ++cc) {
    int col = cc * 16 + m;
#pragma unroll
    for (int g = 0; g < 4; ++g)
      TB[lofs(quad * 4 + g, col)] = f2b(lrelu(acc[cc][g] + bv[cc]));
  }
  WAVE_SYNC();

  // ---- stage 2: h3 = leaky(m@Wm2+bm2+f2); p = 0.5*(h3+gen) ----
#pragma unroll
  for (int cc = 0; cc < 8; ++cc) bv[cc] = BI[128 + cc * 16 + m];
  lds_afrags16(TB, m, quad, af);  // consume m into regs
  WAVE_SYNC();                    // af loaded before TB is overwritten
  // park gen (regs) into TB, same staging layout
#pragma unroll
  for (int i = 0; i < 8; ++i) {
    int idx = i * 64 + lane;
    int r = idx >> 5, c4 = (idx & 31) << 2;
    *(ushort4*)&TB[lofs(r, c4)] = genb[i];
  }
  mfma_stage(af, (const bf16x8*)Wm2p, lane, acc);
  WAVE_SYNC();                    // gen writes visible for the epilogue reads
#pragma unroll
  for (int cc = 0; cc < 8; ++cc) {
    int col = cc * 16 + m;
#pragma unroll
    for (int g = 0; g < 4; ++g) {
      int lr = quad * 4 + g;
      float f2v = b2f(TA[lofs(lr, col)]);   // residual (same-lane slot)
      float v = lrelu(acc[cc][g] + bv[cc] + f2v);
      float gv = b2f(TB[lofs(lr, col)]);    // gen parked in TB
      TA[lofs(lr, col)] = f2b(0.5f * (v + gv));
    }
  }
  WAVE_SYNC();

  // ---- stage 3: q = leaky(p@Wp1+bp1), Ta -> Tb (gen in TB is dead now) ----
#pragma unroll
  for (int cc = 0; cc < 8; ++cc) bv[cc] = BI[256 + cc * 16 + m];
  lds_afrags16(TA, m, quad, af);
  mfma_stage(af, (const bf16x8*)Wp1p, lane, acc);
#pragma unroll
  for (int cc = 0; cc < 8; ++cc) {
    int col = cc * 16 + m;
#pragma unroll
    for (int g = 0; g < 4; ++g)
      TB[lofs(quad * 4 + g, col)] = f2b(lrelu(acc[cc][g] + bv[cc]));
  }
  WAVE_SYNC();

  // ---- stage 4: out = leaky(q@Wp2+bp2), Tb -> global fp32 ----
#pragma unroll
  for (int cc = 0; cc < 8; ++cc) bv[cc] = BI[384 + cc * 16 + m];
  lds_afrags16(TB, m, quad, af);
  mfma_stage(af, (const bf16x8*)Wp2p, lane, acc);
#pragma unroll
  for (int cc = 0; cc < 8; ++cc) {
    int col = cc * 16 + m;
#pragma unroll
    for (int g = 0; g < 4; ++g) {
      int row = row0 + quad * 4 + g;
      if (row < n) out[(size_t)row * HH + col] = lrelu(acc[cc][g] + bv[cc]);
    }
  }
}

// ---------------- launcher ----------------

extern "C" void kernel_launch(void* const* d_in, const int* in_sizes, int n_in,
                              void* d_out, int out_size, void* d_ws, size_t ws_size,
                              hipStream_t stream) {
  const float* x   = (const float*)d_in[0];
  const int* ei    = (const int*)d_in[1];
  const float* gen = (const float*)d_in[2];
  const float* Wc1 = (const float*)d_in[3];
  const float* bc1 = (const float*)d_in[4];
  const float* Wc2 = (const float*)d_in[5];
  const float* bc2 = (const float*)d_in[6];
  const float* Wm1 = (const float*)d_in[7];
  const float* bm1 = (const float*)d_in[8];
  const float* Wm2 = (const float*)d_in[9];
  const float* bm2 = (const float*)d_in[10];
  const float* Wp1 = (const float*)d_in[11];
  const float* bp1 = (const float*)d_in[12];
  const float* Wp2 = (const float*)d_in[13];
  const float* bp2 = (const float*)d_in[14];

  const int N = in_sizes[0] / HH;
  const int E = in_sizes[1] / 2;
  const int* src = ei;
  const int* dst = ei + E;

  char* ws = (char*)d_ws;
  size_t off = 0;
  auto alloc = [&](size_t bytes) { void* p = ws + off; off += (bytes + 255) & ~(size_t)255; return p; };
  float* dinv            = (float*)alloc((size_t)N * 4);
  int*   rowptr          = (int*)  alloc((size_t)(N + 1) * 4);
  int*   cursor          = (int*)  alloc((size_t)N * 4);
  int*   bsum            = (int*)  alloc((size_t)64 * 4);
  int2*  csr             = (int2*) alloc((size_t)E * 8);
  unsigned short* h_bf   = (unsigned short*)alloc((size_t)N * HH * 2);
  unsigned short* t2_bf  = (unsigned short*)alloc((size_t)N * HH * 2);
  unsigned short* f2_bf  = (unsigned short*)alloc((size_t)N * HH * 2);
  float* f1_f32          = (float*)alloc((size_t)N * HH * 4);
  unsigned short* packed = (unsigned short*)alloc((size_t)6 * 16384 * 2);
  float* fOut = (float*)d_out;

  const int cblocks = (N + 63) / 64;      // 4 waves x 16 rows per 256-thr block
  const int eblocks = (E + 255) / 256;
  const int ablocks = (N + 3) / 4;
  const int sblocks = (N + 1023) / 1024;  // <= 64 for N <= 65536

  // weight packing
  pack_kernel<<<dim3(64, 6), 256, 0, stream>>>(Wc1, Wc2, Wm1, Wm2, Wp1, Wp2, packed);

  // CSR build
  hipMemsetAsync(cursor, 0, (size_t)N * 4, stream);
  count_kernel<<<eblocks, 256, 0, stream>>>(dst, cursor, E);
  scan1_kernel<<<sblocks, 1024, 0, stream>>>(cursor, rowptr, bsum, dinv, N);
  scan2_kernel<<<1, 64, 0, stream>>>(bsum, sblocks, rowptr, N, E);
  scan3_kernel<<<sblocks, 1024, 0, stream>>>(rowptr, bsum, N);
  fill_kernel<<<eblocks, 256, 0, stream>>>(src, dst, rowptr, cursor, dinv, csr, E);

  // conv1: h_bf = bf16(x @ Wc1)
  gemm_conv<<<cblocks, 256, 0, stream>>>(x, packed + 0 * 16384, h_bf, N);
  // agg1: f1 = leaky(agg(h_bf)+self+bc1)  [fp32]
  agg_kernel<0, 0><<<ablocks, 256, 0, stream>>>(h_bf, rowptr, csr, dinv, bc1, nullptr, f1_f32, N);
  // conv2: t2 = bf16(f1 @ Wc2)
  gemm_conv<<<cblocks, 256, 0, stream>>>(f1_f32, packed + 1 * 16384, t2_bf, N);
  // agg2: f2 = leaky(agg(t2)+self+bc2+f1)  [bf16 — only consumed as bf16]
  agg_kernel<1, 1><<<ablocks, 256, 0, stream>>>(t2_bf, rowptr, csr, dinv, bc2, f1_f32, f2_bf, N);
  // fusedMLP: MLP + interp + proj -> d_out
  fusedMLP<<<cblocks, 256, 0, stream>>>(f2_bf,
                                        packed + 2 * 16384, packed + 3 * 16384,
                                        packed + 4 * 16384, packed + 5 * 16384,
                                        bm1, bm2, bp1, bp2, gen, fOut, N);
}